// Round 8
// baseline (667.340 us; speedup 1.0000x reference)
//
#include <hip/hip_runtime.h>
#include <stdint.h>

#define T_ 512
#define B_ 32
#define V_ 512
#define L_ 128
#define NEGF (-1000000000.0f)

// Signed-i8 quantization: E = exp(trans) in ~[0.55,1.83]; SE*1.83 < 127.
#define SE_Q 69.0f
#define SU_Q 127.0f
#define LOGC 9.078313f   /* log(SE_Q * SU_Q) */

typedef int v4i __attribute__((ext_vector_type(4)));

// ---- DPP helpers (VALU pipe) ----------------------------------------------
template <int CTRL>
__device__ __forceinline__ int dppmov(int old_, int src) {
    return __builtin_amdgcn_update_dpp(old_, src, CTRL, 0xF, 0xF, false);
}
__device__ __forceinline__ float wave_max64(float x) {
    int xi = __float_as_int(x);
    x = fmaxf(x, __int_as_float(dppmov<0x111>(xi, xi))); xi = __float_as_int(x);
    x = fmaxf(x, __int_as_float(dppmov<0x112>(xi, xi))); xi = __float_as_int(x);
    x = fmaxf(x, __int_as_float(dppmov<0x114>(xi, xi))); xi = __float_as_int(x);
    x = fmaxf(x, __int_as_float(dppmov<0x118>(xi, xi))); xi = __float_as_int(x);
    x = fmaxf(x, __int_as_float(dppmov<0x142>(xi, xi))); xi = __float_as_int(x);
    x = fmaxf(x, __int_as_float(dppmov<0x143>(xi, xi)));
    return x;   // fully reduced in lane 63
}
__device__ __forceinline__ float wave_sum64(float x) {
    int xi = __float_as_int(x);
    x = x + __int_as_float(dppmov<0x111>(xi, xi)); xi = __float_as_int(x);
    x = x + __int_as_float(dppmov<0x112>(xi, xi)); xi = __float_as_int(x);
    x = x + __int_as_float(dppmov<0x114>(xi, xi)); xi = __float_as_int(x);
    x = x + __int_as_float(dppmov<0x118>(xi, xi)); xi = __float_as_int(x);
    x = x + __int_as_float(dppmov<0x142>(xi, xi)); xi = __float_as_int(x);
    x = x + __int_as_float(dppmov<0x143>(xi, xi));
    return x;
}
// monotonic float<->uint for LDS atomicMax (epilogue only)
__device__ __forceinline__ unsigned fkey(float f) {
    unsigned u = __float_as_uint(f);
    return (u & 0x80000000u) ? ~u : (u | 0x80000000u);
}
__device__ __forceinline__ float funkey(unsigned k) {
    unsigned u = (k & 0x80000000u) ? (k ^ 0x80000000u) : ~k;
    return __uint_as_float(u);
}
// select element r (0..3) of a v4i — 3 cndmask, no scratch
__device__ __forceinline__ int sel4(v4i a, int r) {
    int x0 = (r & 1) ? a.y : a.x;
    int x1 = (r & 1) ? a.w : a.z;
    return (r & 2) ? x1 : x0;
}

// ---------------- prep: quantize E into MFMA A-fragment layout --------------
// asg_main thread tid (512 thr): w=tid>>6, lane=tid&63, q=lane>>4, n=lane&15.
// Wave w owns rows 64w..64w+63 as 4 M-tiles (tt) x 8 K-tiles (kt).
// A-frag for (tt,kt): lane holds A[m=64w+16tt+n][k=64kt+16q+4d+b], d=0..3,b=0..3.
// er4[tt*8+kt] = Eq[(tt*8+kt)*512 + tid]  ->  flat dword o = (qreg*512+tid)*4+d.
__global__ void asg_prep(const float* __restrict__ trans, uint32_t* __restrict__ Et) {
    int o = blockIdx.x * blockDim.x + threadIdx.x;      // 0 .. 65535
    int d    = o & 3;
    int tid  = (o >> 2) & 511;
    int qreg = o >> 11;                                  // 0..31
    int tt = qreg >> 3, kt = qreg & 7;
    int w = tid >> 6, lane = tid & 63;
    int q = lane >> 4, n = lane & 15;
    int m  = 64 * w + 16 * tt + n;
    int k0 = 64 * kt + 16 * q + 4 * d;
    const float* tp = trans + (size_t)m * V_ + k0;
    uint32_t q0 = (uint32_t)fminf(127.0f, __expf(tp[0]) * SE_Q + 0.5f);
    uint32_t q1 = (uint32_t)fminf(127.0f, __expf(tp[1]) * SE_Q + 0.5f);
    uint32_t q2 = (uint32_t)fminf(127.0f, __expf(tp[2]) * SE_Q + 0.5f);
    uint32_t q3 = (uint32_t)fminf(127.0f, __expf(tp[3]) * SE_Q + 0.5f);
    Et[(size_t)o] = q0 | (q1 << 8) | (q2 << 16) | (q3 << 24);
}

// ---------------- fused main: blocks 0..31 = FCC(b), 32..63 = FAC(b-32) -----
// FCC single-barrier step (R1 numerics + R2 MFMA engine + R4 implicit alpha):
//   key = elp*accf -> wave max (DPP) -> kmax_w broadcast via readlane(63)
//   (NO LDS round-trip, NO barrier gates the quantize) -> u8 vs OWN wave max,
//   quad-pack -> u_lds[buf]; lane63 stores kmax_w -> mw_lds[buf] -> ONE barrier
//   -> read 8 B-frags + 8 wave maxes; per chunk kt: 4 independent MFMAs (C=0),
//   ownership mux, fp32 combine accf = sum_kt (kmax_w[kt]/kg) * p[kt]
//   (chunk scales consumed late, hidden under the MFMA phase).
// Double-buffered u_lds/mw_lds make the single barrier race-free.
__global__ __attribute__((amdgpu_flat_work_group_size(512, 512),
                          amdgpu_waves_per_eu(2, 2)))
void asg_main(
    const float* __restrict__ lp, const uint32_t* __restrict__ Et,
    const float* __restrict__ trans, const int* __restrict__ targets,
    const int* __restrict__ ilen, const int* __restrict__ tlen,
    float* __restrict__ fcc_ws, float* __restrict__ fac_ws)
{
    __shared__ float facb[256];                          // fac double buffer
    __shared__ __align__(16) uint32_t u_lds[2][128];     // u8[512] x2 buffers
    __shared__ __align__(16) float mw_lds[2][8];         // per-wave maxes x2
    __shared__ unsigned mslotE;
    __shared__ float sumf;

    const int bb  = blockIdx.x;
    const int tid = threadIdx.x;

    if (bb < B_) {
        // ================= FCC ============================================
        const int b    = bb;
        const int lane = tid & 63;
        const int w    = tid >> 6;              // wave 0..7, rows 64w..64w+63
        const int q    = lane >> 4;             // 0..3
        const int n    = lane & 15;             // 0..15
        const int tt_o = n >> 2;                // owned tile
        const int rg_o = n & 3;                 // owned reg (row-in-4)
        const int i    = 64 * w + 16 * tt_o + 4 * q + rg_o;   // owned row
        const int Tlen = ilen[b];

        // er: 32 uint4 A-frags, lane-coalesced one-time load (dumb loads ->
        // AGPR-resident on gfx950's unified file; MFMA reads A from AGPR)
        uint4 er4[32];
        {
            const uint4* Eq = (const uint4*)Et;
            #pragma unroll
            for (int t8 = 0; t8 < 32; ++t8) er4[t8] = Eq[t8 * 512 + tid];
        }

        // ---- implicit-alpha state: alpha = lpv + S + log(accf)
        float lpv0 = lp[(size_t)b * V_ + i];                          // t=0
        float elp  = __expf(lpv0);                                    // exp(lp[t-1])
        float lpv  = lp[(size_t)(B_ * V_) + (size_t)b * V_ + i];      // lp[t]
        float accf = 1.0f;
        float S    = 0.0f;
        if (tid == 0) { mslotE = 0u; sumf = 0.0f; }
        __syncthreads();

        for (int t = 1; t < Tlen; ++t) {
            const int bi = t & 1;
            float key = elp * accf;             // = exp(alpha_prev - S)

            // ---- wave max of key, broadcast via readlane (no LDS, no barrier)
            float mxw = wave_max64(key);
            float kmax_w = __int_as_float(
                __builtin_amdgcn_readlane(__float_as_int(mxw), 63));
            kmax_w = fmaxf(kmax_w, 1e-30f);     // NaN guard (never binds here)
            float r127 = 127.0f * __builtin_amdgcn_rcpf(kmax_w);

            // ---- u8 = round(127*key/kmax_w), quad-packed to LDS byte i
            {
                uint32_t qu = (uint32_t)fminf(127.0f, fmaf(key, r127, 0.5f));
                int pv = (int)(qu << (8 * (i & 3)));   // i&3 == lane bits 0-1
                pv |= dppmov<0xB1>(pv, pv);
                pv |= dppmov<0x4E>(pv, pv);
                if ((i & 3) == 0) u_lds[bi][i >> 2] = (uint32_t)pv;
            }
            if (lane == 63) mw_lds[bi][w] = kmax_w;
            float elp_n = __expf(lpv);          // off critical path
            __syncthreads();                    // ONE barrier/step

            // ---- B-frags + chunk maxes (scales consumed late, under MFMA)
            uint4 bf[8];
            #pragma unroll
            for (int kt = 0; kt < 8; ++kt)
                bf[kt] = *(const uint4*)((const char*)u_lds[bi] + 64 * kt + 16 * q);
            float4 mv0 = *(const float4*)&mw_lds[bi][0];
            float4 mv1 = *(const float4*)&mw_lds[bi][4];

            // prefetch next lp (in flight over the MFMA phase)
            int tn = (t + 1 < Tlen) ? (t + 1) : t;
            float lpv_n = lp[(size_t)tn * (B_ * V_) + (size_t)b * V_ + i];

            float kg = fmaxf(fmaxf(fmaxf(mv0.x, mv0.y), fmaxf(mv0.z, mv0.w)),
                             fmaxf(fmaxf(mv1.x, mv1.y), fmaxf(mv1.z, mv1.w)));
            float rkg = __builtin_amdgcn_rcpf(kg);
            float s0 = mv0.x * rkg, s1 = mv0.y * rkg;
            float s2 = mv0.z * rkg, s3 = mv0.w * rkg;
            float s4 = mv1.x * rkg, s5 = mv1.y * rkg;
            float s6 = mv1.z * rkg, s7 = mv1.w * rkg;

            // ---- per chunk: 4 independent MFMAs (C=0) + ownership mux
            int p[8];
            {
                v4i z = {0, 0, 0, 0};
                #pragma unroll
                for (int kt = 0; kt < 8; ++kt) {
                    v4i bv = __builtin_bit_cast(v4i, bf[kt]);
                    v4i a0 = __builtin_amdgcn_mfma_i32_16x16x64_i8(
                                __builtin_bit_cast(v4i, er4[0 * 8 + kt]), bv, z, 0, 0, 0);
                    v4i a1 = __builtin_amdgcn_mfma_i32_16x16x64_i8(
                                __builtin_bit_cast(v4i, er4[1 * 8 + kt]), bv, z, 0, 0, 0);
                    v4i a2 = __builtin_amdgcn_mfma_i32_16x16x64_i8(
                                __builtin_bit_cast(v4i, er4[2 * 8 + kt]), bv, z, 0, 0, 0);
                    v4i a3 = __builtin_amdgcn_mfma_i32_16x16x64_i8(
                                __builtin_bit_cast(v4i, er4[3 * 8 + kt]), bv, z, 0, 0, 0);
                    int x0 = sel4(a0, rg_o), x1 = sel4(a1, rg_o);
                    int x2 = sel4(a2, rg_o), x3 = sel4(a3, rg_o);
                    int y0 = (tt_o & 1) ? x1 : x0;
                    int y1 = (tt_o & 1) ? x3 : x2;
                    p[kt] = (tt_o & 2) ? y1 : y0;
                }
            }

            // ---- fp32 combine (tree): accf = sum_kt s[kt] * p[kt]
            float t0 = fmaf(s0, (float)p[0], s1 * (float)p[1]);
            float t1 = fmaf(s2, (float)p[2], s3 * (float)p[3]);
            float t2 = fmaf(s4, (float)p[4], s5 * (float)p[5]);
            float t3 = fmaf(s6, (float)p[6], s7 * (float)p[7]);
            accf = (t0 + t1) + (t2 + t3);

            S += __logf(kg) - LOGC;             // uniform; epilogue-only
            elp = elp_n;
            lpv = lpv_n;
        }

        // ---- epilogue: reconstruct alpha, exact f32 logsumexp over 512 rows
        float alpha = ((Tlen > 1) ? lpv : lpv0) + S + __logf(accf);
        {
            float mx = wave_max64(alpha);
            if (lane == 63) atomicMax(&mslotE, fkey(mx));
        }
        __syncthreads();
        float m2 = funkey(mslotE);
        {
            float sv = wave_sum64(__expf(alpha - m2));
            if (lane == 63) atomicAdd(&sumf, sv);
        }
        __syncthreads();
        if (tid == 0) fcc_ws[b] = m2 + __logf(sumf);
    } else {
        // ================= FAC (threads 0..127 active) =====================
        const int b = bb - B_;
        const int l = tid;
        const bool active = (l < L_);
        const int Tlen = ilen[b];
        const int Llen = tlen[b];

        const int tl  = active ? targets[b * L_ + l] : 0;
        const int tlm = (active && l > 0) ? targets[b * L_ + l - 1] : 0;
        const float ts = active ? trans[(size_t)tl * V_ + tl] : 0.0f;
        const float tp = (active && l > 0) ? trans[(size_t)tl * V_ + tlm] : 0.0f;

        float beta = (l == 0) ? lp[(size_t)b * V_ + tl] : NEGF;
        float em_next = active ? lp[(size_t)1 * (B_ * V_) + (size_t)b * V_ + tl] : 0.0f;

        for (int t = 1; t < Tlen; ++t) {
            float* buf = facb + (t & 1) * L_;
            if (active) buf[l] = beta;
            __syncthreads();
            float prev = (active && l > 0) ? buf[l - 1] : NEGF;
            float em = em_next;
            if (active && t + 1 < Tlen)
                em_next = lp[(size_t)(t + 1) * (B_ * V_) + (size_t)b * V_ + tl];
            if (active) {
                float st = beta + ts;
                float mv = prev + tp;
                float mx = fmaxf(st, mv);
                float mn = fminf(st, mv);
                beta = em + mx + log1pf(__expf(mn - mx));
            }
        }
        if (active && l == Llen - 1) fac_ws[b] = beta;
    }
}

// ---------------- combine ---------------------------------------------------
__global__ void asg_combine(const float* __restrict__ fcc_ws,
                            const float* __restrict__ fac_ws,
                            float* __restrict__ out) {
    int i = threadIdx.x;
    if (i < B_) out[i] = fcc_ws[i] - fac_ws[i];
}

extern "C" void kernel_launch(void* const* d_in, const int* in_sizes, int n_in,
                              void* d_out, int out_size, void* d_ws, size_t ws_size,
                              hipStream_t stream) {
    const float* lp      = (const float*)d_in[0];
    const float* trans   = (const float*)d_in[1];
    const int*   targets = (const int*)d_in[2];
    const int*   ilen    = (const int*)d_in[3];
    const int*   tlen    = (const int*)d_in[4];
    float* out = (float*)d_out;

    uint32_t* Et     = (uint32_t*)d_ws;                    // 65536 dwords = 256 KB
    float*    fcc_ws = (float*)((char*)d_ws + 65536 * 4);
    float*    fac_ws = fcc_ws + B_;

    hipLaunchKernelGGL(asg_prep, dim3(256), dim3(256), 0, stream, trans, Et);
    hipLaunchKernelGGL(asg_main, dim3(2 * B_), dim3(512), 0, stream,
                       lp, Et, trans, targets, ilen, tlen, fcc_ws, fac_ws);
    hipLaunchKernelGGL(asg_combine, dim3(1), dim3(64), 0, stream, fcc_ws, fac_ws, out);
}